// Round 1
// baseline (260.674 us; speedup 1.0000x reference)
//
#include <hip/hip_runtime.h>

constexpr int HIDDEN = 1024;
constexpr int BATCH  = 32;
constexpr int SRC    = 4096;

// ---------- helpers ----------

__device__ __forceinline__ float wave_reduce_add(float v) {
    #pragma unroll
    for (int off = 32; off > 0; off >>= 1)
        v += __shfl_down(v, off, 64);
    return v;
}

// Dot of one 1024-f32 row (as float4[256]) against the wave's register-held
// query fragments (lane l holds q indices l, l+64, l+128, l+192 as float4).
__device__ __forceinline__ float row_dot(const float4* __restrict__ row, int lane,
                                         float4 q0, float4 q1, float4 q2, float4 q3) {
    float4 a = row[lane];
    float4 b = row[lane + 64];
    float4 c = row[lane + 128];
    float4 d = row[lane + 192];
    float acc = a.x*q0.x + a.y*q0.y + a.z*q0.z + a.w*q0.w
              + b.x*q1.x + b.y*q1.y + b.z*q1.z + b.w*q1.w
              + c.x*q2.x + c.y*q2.y + c.z*q2.z + c.w*q2.w
              + d.x*q3.x + d.y*q3.y + d.z*q3.z + d.w*q3.w;
    return wave_reduce_add(acc);
}

// ---------- K1: proj[b,o] = sum_i query[b,i] * W[o,i] ----------
// grid (BATCH, HIDDEN/256), block 256 (4 waves x 64 rows each)
__global__ __launch_bounds__(256) void k_proj(const float* __restrict__ query,
                                              const float* __restrict__ W,
                                              float* __restrict__ proj) {
    int b   = blockIdx.x;
    int oc  = blockIdx.y;
    int wid = threadIdx.x >> 6, lane = threadIdx.x & 63;
    const float4* q4 = (const float4*)(query + (size_t)b * HIDDEN);
    float4 q0 = q4[lane], q1 = q4[lane + 64], q2 = q4[lane + 128], q3 = q4[lane + 192];
    int o_base = oc * 256 + wid * 64;
    for (int i = 0; i < 64; ++i) {
        int o = o_base + i;
        const float4* wrow = (const float4*)(W + (size_t)o * HIDDEN);
        float s = row_dot(wrow, lane, q0, q1, q2, q3);
        if (lane == 0) proj[b * HIDDEN + o] = s;
    }
}

// ---------- K2: scores[b,s] = keys[b,s,:] . proj[b,:], masked ----------
// grid (BATCH, SRC/128), block 256 (4 waves x 32 rows each)
__global__ __launch_bounds__(256) void k_scores(const float* __restrict__ keys,
                                                const float* __restrict__ proj,
                                                const int* __restrict__ mask,
                                                float* __restrict__ scores) {
    int b   = blockIdx.x;
    int ch  = blockIdx.y;
    int wid = threadIdx.x >> 6, lane = threadIdx.x & 63;
    const float4* p4 = (const float4*)(proj + (size_t)b * HIDDEN);
    float4 q0 = p4[lane], q1 = p4[lane + 64], q2 = p4[lane + 128], q3 = p4[lane + 192];
    int s_base = ch * 128 + wid * 32;
    for (int i = 0; i < 32; ++i) {
        int s = s_base + i;
        const float4* krow = (const float4*)(keys + ((size_t)b * SRC + s) * HIDDEN);
        float sc = row_dot(krow, lane, q0, q1, q2, q3);
        if (lane == 0) {
            scores[b * SRC + s] = mask[b * SRC + s] ? -__builtin_inff() : sc;
        }
    }
}

// ---------- K3: softmax over S per batch; writes attn to d_out ----------
// grid BATCH, block 256
__global__ __launch_bounds__(256) void k_softmax(const float* __restrict__ scores,
                                                 float* __restrict__ attn) {
    int b = blockIdx.x, tid = threadIdx.x;
    int wid = tid >> 6, lane = tid & 63;
    __shared__ float sl[SRC];          // 16 KB
    __shared__ float red[8];

    const float4* s4  = (const float4*)(scores + (size_t)b * SRC);
    float4*       sl4 = (float4*)sl;
    float lmax = -__builtin_inff();
    #pragma unroll
    for (int j = tid; j < SRC / 4; j += 256) {
        float4 v = s4[j];
        sl4[j] = v;
        lmax = fmaxf(lmax, fmaxf(fmaxf(v.x, v.y), fmaxf(v.z, v.w)));
    }
    #pragma unroll
    for (int off = 32; off > 0; off >>= 1)
        lmax = fmaxf(lmax, __shfl_down(lmax, off, 64));
    if (lane == 0) red[wid] = lmax;
    __syncthreads();
    float m = fmaxf(fmaxf(red[0], red[1]), fmaxf(red[2], red[3]));

    float lsum = 0.f;
    for (int j = tid; j < SRC; j += 256) lsum += __expf(sl[j] - m);
    lsum = wave_reduce_add(lsum);
    if (lane == 0) red[4 + wid] = lsum;
    __syncthreads();
    float inv = 1.f / (red[4] + red[5] + red[6] + red[7]);

    for (int j = tid; j < SRC; j += 256)
        attn[b * SRC + j] = __expf(sl[j] - m) * inv;
}

// ---------- K4a: partial context over s-chunks ----------
// grid (BATCH, 32), block 256; each thread owns 4 h (float4)
__global__ __launch_bounds__(256) void k_ctx_part(const float* __restrict__ values,
                                                  const float* __restrict__ attn,
                                                  float* __restrict__ part) {
    int b = blockIdx.x, ch = blockIdx.y, tid = threadIdx.x;
    int s0 = ch * 128;
    const float*  ap = attn + (size_t)b * SRC + s0;
    const float4* v4 = (const float4*)(values + ((size_t)b * SRC + s0) * HIDDEN);
    float4 acc = {0.f, 0.f, 0.f, 0.f};
    #pragma unroll 4
    for (int i = 0; i < 128; ++i) {
        float  w = ap[i];                 // uniform address -> scalar load
        float4 v = v4[(size_t)i * 256 + tid];
        acc.x += w * v.x; acc.y += w * v.y; acc.z += w * v.z; acc.w += w * v.w;
    }
    ((float4*)(part + ((size_t)(b * 32 + ch)) * HIDDEN))[tid] = acc;
}

// ---------- K4b: reduce partials -> context ----------
// grid BATCH, block 256
__global__ __launch_bounds__(256) void k_ctx_reduce(const float* __restrict__ part,
                                                    float* __restrict__ ctx) {
    int b = blockIdx.x, tid = threadIdx.x;
    const float4* p4 = (const float4*)(part + (size_t)b * 32 * HIDDEN);
    float4 acc = {0.f, 0.f, 0.f, 0.f};
    #pragma unroll
    for (int c = 0; c < 32; ++c) {
        float4 v = p4[c * 256 + tid];
        acc.x += v.x; acc.y += v.y; acc.z += v.z; acc.w += v.w;
    }
    ((float4*)(ctx + (size_t)b * HIDDEN))[tid] = acc;
}

// ---------- launch ----------
extern "C" void kernel_launch(void* const* d_in, const int* in_sizes, int n_in,
                              void* d_out, int out_size, void* d_ws, size_t ws_size,
                              hipStream_t stream) {
    const float* query  = (const float*)d_in[0];
    const float* keys   = (const float*)d_in[1];
    const float* values = (const float*)d_in[2];
    const int*   mask   = (const int*)d_in[3];
    const float* W      = (const float*)d_in[4];

    float* ctx  = (float*)d_out;                  // (32, 1024)
    float* attn = (float*)d_out + BATCH * HIDDEN; // (32, 4096)

    float* proj   = (float*)d_ws;                 // 32768 f32
    float* scores = proj + BATCH * HIDDEN;        // 131072 f32
    float* part   = scores + BATCH * SRC;         // 32*32*1024 f32 = 4 MB

    k_proj      <<<dim3(BATCH, HIDDEN / 256), 256, 0, stream>>>(query, W, proj);
    k_scores    <<<dim3(BATCH, SRC / 128),    256, 0, stream>>>(keys, proj, mask, scores);
    k_softmax   <<<dim3(BATCH),               256, 0, stream>>>(scores, attn);
    k_ctx_part  <<<dim3(BATCH, 32),           256, 0, stream>>>(values, attn, part);
    k_ctx_reduce<<<dim3(BATCH),               256, 0, stream>>>(part, ctx);
}